// Round 9
// baseline (42.268 us; speedup 1.0000x reference)
//
#include <hip/hip_runtime.h>
#include <math.h>

namespace {

constexpr int kL       = 2048;  // sequence length
constexpr int kThreads = 512;   // 8 waves
constexpr int kBlkPos  = 128;   // 8 waves x 16 positions -> 512 blocks, one round
constexpr int kPosPerWave = 16;

typedef float    vfloat4 __attribute__((ext_vector_type(4)));
typedef _Float16 half4   __attribute__((ext_vector_type(4)));
typedef _Float16 half2   __attribute__((ext_vector_type(2)));

// x += dpp_move(x); all-VALU, no LDS.
template <int CTRL, int RM, bool BC>
__device__ __forceinline__ float dpp_acc(float x) {
    const int y = __builtin_amdgcn_update_dpp(0, __float_as_int(x), CTRL, RM, 0xF, BC);
    return x + __int_as_float(y);
}

// Full 64-lane sum, result broadcast via readlane(63).
__device__ __forceinline__ float wave_sum(float x) {
    x = dpp_acc<0xB1,  0xF, true >(x);  // quad_perm xor1
    x = dpp_acc<0x4E,  0xF, true >(x);  // quad_perm xor2
    x = dpp_acc<0x124, 0xF, true >(x);  // row_ror:4
    x = dpp_acc<0x128, 0xF, true >(x);  // row_ror:8 -> row sums
    x = dpp_acc<0x142, 0xA, false>(x);  // row_bcast15 -> rows 1,3
    x = dpp_acc<0x143, 0xC, false>(x);  // row_bcast31 -> row 3 = total
    return __int_as_float(__builtin_amdgcn_readlane(__float_as_int(x), 63));
}

__device__ __forceinline__ half2 vlo(half4 v) { return __builtin_shufflevector(v, v, 0, 1); }
__device__ __forceinline__ half2 vhi(half4 v) { return __builtin_shufflevector(v, v, 2, 3); }

// One wave per position (16 consecutive positions per wave). fp16 weight
// table in LDS: row = tap*6 + class; class 5 rows are ZERO (sentinel: token 5
// or out-of-range tap) -> no compares in the hot loop. Tap offset (t*3072 B)
// folds into the ds_read immediate. Window addresses rotate across the
// unrolled position loop (1 readlane + 1 mad per position steady-state).
// Stats via v_dot2_f32_f16 + DPP wave reduce. Mask folded analytically.
__global__ __launch_bounds__(kThreads, 4)
void cnn_emb_ln(const int*   __restrict__ ids,     // [B*L] tokens 0..5
                const float* __restrict__ mask,    // [B*L]
                const float* __restrict__ W3,      // [256][5][3]
                const float* __restrict__ W5,      // [256][5][5]
                const float* __restrict__ W7,      // [256][5][7]
                const float* __restrict__ gamma,   // [768]
                const float* __restrict__ beta,    // [768]
                float*       __restrict__ out)     // [B*L][768]
{
    __shared__ half4 sW[90][64];   // 46080 B; row = tap*6 + class

    const int tid  = threadIdx.x;
    const int lane = tid & 63;
    const int wave = tid >> 6;

    _Float16* sWh = reinterpret_cast<_Float16*>(sW);

    // ---- zero the 15 sentinel rows (tap*6 + 5) ----
    for (int i = tid; i < 15 * 64; i += kThreads) {
        const int t = i >> 6, l = i & 63;
        sW[t * 6 + 5][l] = half4{(_Float16)0.f, (_Float16)0.f, (_Float16)0.f, (_Float16)0.f};
    }

    // ---- stage weights: coalesced float4 reads, scattered fp16 LDS writes ----
    {   // W3: 3840 floats, taps 0..2
        const float4* v4 = reinterpret_cast<const float4*>(W3);
        for (int i = tid; i < 960; i += kThreads) {
            const float4 v = v4[i];
            const float f[4] = {v.x, v.y, v.z, v.w};
            #pragma unroll
            for (int j = 0; j < 4; ++j) {
                const int e = 4 * i + j, o = e / 15, r = e % 15;
                sWh[((r % 3) * 6 + (r / 3)) * 256 + o] = (_Float16)f[j];
            }
        }
    }
    {   // W5: 6400 floats, taps 3..7
        const float4* v4 = reinterpret_cast<const float4*>(W5);
        for (int i = tid; i < 1600; i += kThreads) {
            const float4 v = v4[i];
            const float f[4] = {v.x, v.y, v.z, v.w};
            #pragma unroll
            for (int j = 0; j < 4; ++j) {
                const int e = 4 * i + j, o = e / 25, r = e % 25;
                sWh[((3 + r % 5) * 6 + (r / 5)) * 256 + o] = (_Float16)f[j];
            }
        }
    }
    {   // W7: 8960 floats, taps 8..14
        const float4* v4 = reinterpret_cast<const float4*>(W7);
        for (int i = tid; i < 2240; i += kThreads) {
            const float4 v = v4[i];
            const float f[4] = {v.x, v.y, v.z, v.w};
            #pragma unroll
            for (int j = 0; j < 4; ++j) {
                const int e = 4 * i + j, o = e / 35, r = e % 35;
                sWh[((8 + r % 7) * 6 + (r / 7)) * 256 + o] = (_Float16)f[j];
            }
        }
    }

    // ---- per-wave id halo (22) + mask (16) into lane registers ----
    const int p0 = blockIdx.x * kBlkPos + wave * kPosPerWave;
    const int l0 = p0 & (kL - 1);

    int myc = 5;
    if (lane < kPosPerWave + 6) {
        const int lp = l0 - 3 + lane;
        if (lp >= 0 && lp < kL) {
            const int v = ids[p0 - 3 + lane];
            myc = (v < 5) ? v : 5;
        }
    }
    float mym = 0.f;
    if (lane < kPosPerWave) mym = mask[p0 + lane];

    // per-lane gamma/beta, fp32 in registers
    float ga[3][4], be[3][4];
    #pragma unroll
    for (int g = 0; g < 3; ++g) {
        const float4 gg = *reinterpret_cast<const float4*>(gamma + g * 256 + 4 * lane);
        const float4 bb = *reinterpret_cast<const float4*>(beta  + g * 256 + 4 * lane);
        ga[g][0] = gg.x; ga[g][1] = gg.y; ga[g][2] = gg.z; ga[g][3] = gg.w;
        be[g][0] = bb.x; be[g][1] = bb.y; be[g][2] = bb.z; be[g][3] = bb.w;
    }

    __syncthreads();

    const char* wb = reinterpret_cast<const char*>(sW);
    const int lane8 = lane * 8;
    const half2 ones = {(_Float16)1.f, (_Float16)1.f};

    // seed rotating window addresses: a[j] = class(l0-3+j)*512 + lane*8
    int a[7];
    #pragma unroll
    for (int j = 0; j < 7; ++j)
        a[j] = (__builtin_amdgcn_readlane(myc, j) << 9) + lane8;

    #pragma unroll
    for (int i = 0; i < kPosPerWave; ++i) {
        const float m = __int_as_float(__builtin_amdgcn_readlane(__float_as_int(mym), i));

        // tap t lives at byte offset t*3072 within its window's class column
        #define RD(t, aj) (*reinterpret_cast<const half4*>(wb + (aj) + (t) * 3072))
        const half4 a3 = (RD(0, a[2]) + RD(1, a[3])) + RD(2, a[4]);
        const half4 a5 = ((RD(3, a[1]) + RD(4, a[2])) + (RD(5, a[3]) + RD(6, a[4])))
                       + RD(7, a[5]);
        const half4 a7 = ((RD(8, a[0]) + RD(9, a[1])) + (RD(10, a[2]) + RD(11, a[3])))
                       + ((RD(12, a[4]) + RD(13, a[5])) + RD(14, a[6]));
        #undef RD

        // stats via dot2: s = sum(h), ss = sum(h^2), over this lane's 12 ch
        float s3 = __builtin_amdgcn_fdot2(vlo(a3), ones, 0.f, false);
        s3 = __builtin_amdgcn_fdot2(vhi(a3), ones, s3, false);
        float s5 = __builtin_amdgcn_fdot2(vlo(a5), ones, 0.f, false);
        s5 = __builtin_amdgcn_fdot2(vhi(a5), ones, s5, false);
        float s7 = __builtin_amdgcn_fdot2(vlo(a7), ones, 0.f, false);
        s7 = __builtin_amdgcn_fdot2(vhi(a7), ones, s7, false);

        float q3 = __builtin_amdgcn_fdot2(vlo(a3), vlo(a3), 0.f, false);
        q3 = __builtin_amdgcn_fdot2(vhi(a3), vhi(a3), q3, false);
        float q5 = __builtin_amdgcn_fdot2(vlo(a5), vlo(a5), 0.f, false);
        q5 = __builtin_amdgcn_fdot2(vhi(a5), vhi(a5), q5, false);
        float q7 = __builtin_amdgcn_fdot2(vlo(a7), vlo(a7), 0.f, false);
        q7 = __builtin_amdgcn_fdot2(vhi(a7), vhi(a7), q7, false);

        const float s_tot  = wave_sum((s3 + s5) + s7);
        const float ss_tot = wave_sum((q3 + q5) + q7);

        const float inv_n = 1.0f / 768.0f;
        const float mu  = m * s_tot * inv_n;
        const float ex2 = (m * m) * ss_tot * inv_n;
        const float var = fmaxf(ex2 - mu * mu, 0.0f);
        const float rs  = rsqrtf(var + 1e-12f);
        const float aa  = m * rs;          // (m*h - mu)*rs = h*aa + cc
        const float cc  = -mu * rs;

        const float h3[4] = {(float)a3.x, (float)a3.y, (float)a3.z, (float)a3.w};
        const float h5[4] = {(float)a5.x, (float)a5.y, (float)a5.z, (float)a5.w};
        const float h7[4] = {(float)a7.x, (float)a7.y, (float)a7.z, (float)a7.w};

        float* o = out + (size_t)(p0 + i) * 768 + 4 * lane;

        vfloat4 r;
        r.x = fmaf(fmaf(h3[0], aa, cc), ga[0][0], be[0][0]);
        r.y = fmaf(fmaf(h3[1], aa, cc), ga[0][1], be[0][1]);
        r.z = fmaf(fmaf(h3[2], aa, cc), ga[0][2], be[0][2]);
        r.w = fmaf(fmaf(h3[3], aa, cc), ga[0][3], be[0][3]);
        *reinterpret_cast<vfloat4*>(o) = r;

        r.x = fmaf(fmaf(h5[0], aa, cc), ga[1][0], be[1][0]);
        r.y = fmaf(fmaf(h5[1], aa, cc), ga[1][1], be[1][1]);
        r.z = fmaf(fmaf(h5[2], aa, cc), ga[1][2], be[1][2]);
        r.w = fmaf(fmaf(h5[3], aa, cc), ga[1][3], be[1][3]);
        *reinterpret_cast<vfloat4*>(o + 256) = r;

        r.x = fmaf(fmaf(h7[0], aa, cc), ga[2][0], be[2][0]);
        r.y = fmaf(fmaf(h7[1], aa, cc), ga[2][1], be[2][1]);
        r.z = fmaf(fmaf(h7[2], aa, cc), ga[2][2], be[2][2]);
        r.w = fmaf(fmaf(h7[3], aa, cc), ga[2][3], be[2][3]);
        *reinterpret_cast<vfloat4*>(o + 512) = r;

        // rotate window addresses; pull in the next class
        if (i < kPosPerWave - 1) {
            #pragma unroll
            for (int j = 0; j < 6; ++j) a[j] = a[j + 1];
            a[6] = (__builtin_amdgcn_readlane(myc, i + 7) << 9) + lane8;
        }
    }
}

} // namespace

extern "C" void kernel_launch(void* const* d_in, const int* in_sizes, int n_in,
                              void* d_out, int out_size, void* d_ws, size_t ws_size,
                              hipStream_t stream) {
    const int*   ids   = (const int*)  d_in[0];
    const float* mask  = (const float*)d_in[1];
    const float* W3    = (const float*)d_in[2];
    const float* W5    = (const float*)d_in[3];
    const float* W7    = (const float*)d_in[4];
    const float* gamma = (const float*)d_in[5];
    const float* beta  = (const float*)d_in[6];
    float*       out   = (float*)d_out;

    const int npos = in_sizes[0];              // B*L = 65536
    const int grid = npos / kBlkPos;           // 512 blocks; 2/CU -> one clean round

    hipLaunchKernelGGL(cnn_emb_ln, dim3(grid), dim3(kThreads), 0, stream,
                       ids, mask, W3, W5, W7, gamma, beta, out);
}

// Round 11
// 41.799 us; speedup vs baseline: 1.0112x; 1.0112x over previous
//
#include <hip/hip_runtime.h>
#include <math.h>

namespace {

constexpr int kL       = 2048;  // sequence length
constexpr int kThreads = 512;   // 8 waves
constexpr int kBlkPos  = 128;   // 8 waves x 16 positions -> 512 blocks, one round
constexpr int kPosPerWave = 16;

typedef float    vfloat4 __attribute__((ext_vector_type(4)));
typedef _Float16 half4   __attribute__((ext_vector_type(4)));
typedef _Float16 half2   __attribute__((ext_vector_type(2)));

template <int CTRL, int RM, bool BC>
__device__ __forceinline__ float dpp_step(float x) {
    return __int_as_float(__builtin_amdgcn_update_dpp(0, __float_as_int(x), CTRL, RM, 0xF, BC));
}

// Two independent 64-lane sums, DPP steps explicitly interleaved for ILP.
__device__ __forceinline__ void wave_sum2(float& x, float& y) {
    float tx, ty;
    tx = dpp_step<0xB1,  0xF, true >(x);  ty = dpp_step<0xB1,  0xF, true >(y);
    x += tx;                              y += ty;
    tx = dpp_step<0x4E,  0xF, true >(x);  ty = dpp_step<0x4E,  0xF, true >(y);
    x += tx;                              y += ty;
    tx = dpp_step<0x124, 0xF, true >(x);  ty = dpp_step<0x124, 0xF, true >(y);
    x += tx;                              y += ty;
    tx = dpp_step<0x128, 0xF, true >(x);  ty = dpp_step<0x128, 0xF, true >(y);
    x += tx;                              y += ty;
    tx = dpp_step<0x142, 0xA, false>(x);  ty = dpp_step<0x142, 0xA, false>(y);
    x += tx;                              y += ty;
    tx = dpp_step<0x143, 0xC, false>(x);  ty = dpp_step<0x143, 0xC, false>(y);
    x += tx;                              y += ty;
    x = __int_as_float(__builtin_amdgcn_readlane(__float_as_int(x), 63));
    y = __int_as_float(__builtin_amdgcn_readlane(__float_as_int(y), 63));
}

__device__ __forceinline__ half2 vlo(half4 v) { return __builtin_shufflevector(v, v, 0, 1); }
__device__ __forceinline__ half2 vhi(half4 v) { return __builtin_shufflevector(v, v, 2, 3); }

// One wave per position, positions processed in PAIRS (2-way ILP): both
// h-vectors, interleaved DPP reductions, and six disjoint store-data
// registers per pair (store-source regs not redefined until a full pair-body
// later -> no early vmcnt stalls). fp16 table row = tap*6 + class, class 5
// rows zero. Rotating window addresses (rotate by 2 per pair).
__global__ __launch_bounds__(kThreads, 4)
void cnn_emb_ln(const int*   __restrict__ ids,     // [B*L] tokens 0..5
                const float* __restrict__ mask,    // [B*L]
                const float* __restrict__ W3,      // [256][5][3]
                const float* __restrict__ W5,      // [256][5][5]
                const float* __restrict__ W7,      // [256][5][7]
                const float* __restrict__ gamma,   // [768]
                const float* __restrict__ beta,    // [768]
                float*       __restrict__ out)     // [B*L][768]
{
    __shared__ half4 sW[90][64];   // 46080 B; row = tap*6 + class

    const int tid  = threadIdx.x;
    const int lane = tid & 63;
    const int wave = tid >> 6;

    _Float16* sWh = reinterpret_cast<_Float16*>(sW);

    // ---- zero the 15 sentinel rows (tap*6 + 5) ----
    for (int i = tid; i < 15 * 64; i += kThreads) {
        const int t = i >> 6, l = i & 63;
        sW[t * 6 + 5][l] = half4{(_Float16)0.f, (_Float16)0.f, (_Float16)0.f, (_Float16)0.f};
    }

    // ---- stage weights: coalesced float4 reads, scattered fp16 LDS writes ----
    {   // W3: 3840 floats, taps 0..2
        const float4* v4 = reinterpret_cast<const float4*>(W3);
        for (int i = tid; i < 960; i += kThreads) {
            const float4 v = v4[i];
            const float f[4] = {v.x, v.y, v.z, v.w};
            #pragma unroll
            for (int j = 0; j < 4; ++j) {
                const int e = 4 * i + j, o = e / 15, r = e % 15;
                sWh[((r % 3) * 6 + (r / 3)) * 256 + o] = (_Float16)f[j];
            }
        }
    }
    {   // W5: 6400 floats, taps 3..7
        const float4* v4 = reinterpret_cast<const float4*>(W5);
        for (int i = tid; i < 1600; i += kThreads) {
            const float4 v = v4[i];
            const float f[4] = {v.x, v.y, v.z, v.w};
            #pragma unroll
            for (int j = 0; j < 4; ++j) {
                const int e = 4 * i + j, o = e / 25, r = e % 25;
                sWh[((3 + r % 5) * 6 + (r / 5)) * 256 + o] = (_Float16)f[j];
            }
        }
    }
    {   // W7: 8960 floats, taps 8..14
        const float4* v4 = reinterpret_cast<const float4*>(W7);
        for (int i = tid; i < 2240; i += kThreads) {
            const float4 v = v4[i];
            const float f[4] = {v.x, v.y, v.z, v.w};
            #pragma unroll
            for (int j = 0; j < 4; ++j) {
                const int e = 4 * i + j, o = e / 35, r = e % 35;
                sWh[((8 + r % 7) * 6 + (r / 7)) * 256 + o] = (_Float16)f[j];
            }
        }
    }

    // ---- per-wave id halo (22) + mask (16) into lane registers ----
    const int p0 = blockIdx.x * kBlkPos + wave * kPosPerWave;
    const int l0 = p0 & (kL - 1);

    int myc = 5;
    if (lane < kPosPerWave + 6) {
        const int lp = l0 - 3 + lane;
        if (lp >= 0 && lp < kL) {
            const int v = ids[p0 - 3 + lane];
            myc = (v < 5) ? v : 5;
        }
    }
    float mym = 0.f;
    if (lane < kPosPerWave) mym = mask[p0 + lane];

    // per-lane gamma/beta, fp32 in registers
    float ga[3][4], be[3][4];
    #pragma unroll
    for (int g = 0; g < 3; ++g) {
        const float4 gg = *reinterpret_cast<const float4*>(gamma + g * 256 + 4 * lane);
        const float4 bb = *reinterpret_cast<const float4*>(beta  + g * 256 + 4 * lane);
        ga[g][0] = gg.x; ga[g][1] = gg.y; ga[g][2] = gg.z; ga[g][3] = gg.w;
        be[g][0] = bb.x; be[g][1] = bb.y; be[g][2] = bb.z; be[g][3] = bb.w;
    }

    __syncthreads();

    const char* wb = reinterpret_cast<const char*>(sW);
    const int lane8 = lane * 8;
    const half2 ones = {(_Float16)1.f, (_Float16)1.f};
    const float inv_n = 1.0f / 768.0f;

    // rotating window addresses: a[j] = class(l0-3+2i+j)*512 + lane*8
    int a[8];
    #pragma unroll
    for (int j = 0; j < 8; ++j)
        a[j] = (__builtin_amdgcn_readlane(myc, j) << 9) + lane8;

    #pragma unroll
    for (int i = 0; i < kPosPerWave / 2; ++i) {
        const float mA = __int_as_float(__builtin_amdgcn_readlane(__float_as_int(mym), 2 * i));
        const float mB = __int_as_float(__builtin_amdgcn_readlane(__float_as_int(mym), 2 * i + 1));

        // tap t at byte offset t*3072; pos A uses a[0..6], pos B uses a[1..7]
        #define RD(t, aj) (*reinterpret_cast<const half4*>(wb + (aj) + (t) * 3072))
        const half4 A3 = (RD(0, a[2]) + RD(1, a[3])) + RD(2, a[4]);
        const half4 B3 = (RD(0, a[3]) + RD(1, a[4])) + RD(2, a[5]);
        const half4 A5 = ((RD(3, a[1]) + RD(4, a[2])) + (RD(5, a[3]) + RD(6, a[4]))) + RD(7, a[5]);
        const half4 B5 = ((RD(3, a[2]) + RD(4, a[3])) + (RD(5, a[4]) + RD(6, a[5]))) + RD(7, a[6]);
        const half4 A7 = ((RD(8, a[0]) + RD(9, a[1])) + (RD(10, a[2]) + RD(11, a[3])))
                       + ((RD(12, a[4]) + RD(13, a[5])) + RD(14, a[6]));
        const half4 B7 = ((RD(8, a[1]) + RD(9, a[2])) + (RD(10, a[3]) + RD(11, a[4])))
                       + ((RD(12, a[5]) + RD(13, a[6])) + RD(14, a[7]));
        #undef RD

        // stats via dot2 (per-lane 12 channels each position)
        float sA = __builtin_amdgcn_fdot2(vlo(A3), ones, 0.f, false);
        sA = __builtin_amdgcn_fdot2(vhi(A3), ones, sA, false);
        sA = __builtin_amdgcn_fdot2(vlo(A5), ones, sA, false);
        sA = __builtin_amdgcn_fdot2(vhi(A5), ones, sA, false);
        sA = __builtin_amdgcn_fdot2(vlo(A7), ones, sA, false);
        sA = __builtin_amdgcn_fdot2(vhi(A7), ones, sA, false);
        float qA = __builtin_amdgcn_fdot2(vlo(A3), vlo(A3), 0.f, false);
        qA = __builtin_amdgcn_fdot2(vhi(A3), vhi(A3), qA, false);
        qA = __builtin_amdgcn_fdot2(vlo(A5), vlo(A5), qA, false);
        qA = __builtin_amdgcn_fdot2(vhi(A5), vhi(A5), qA, false);
        qA = __builtin_amdgcn_fdot2(vlo(A7), vlo(A7), qA, false);
        qA = __builtin_amdgcn_fdot2(vhi(A7), vhi(A7), qA, false);
        float sB = __builtin_amdgcn_fdot2(vlo(B3), ones, 0.f, false);
        sB = __builtin_amdgcn_fdot2(vhi(B3), ones, sB, false);
        sB = __builtin_amdgcn_fdot2(vlo(B5), ones, sB, false);
        sB = __builtin_amdgcn_fdot2(vhi(B5), ones, sB, false);
        sB = __builtin_amdgcn_fdot2(vlo(B7), ones, sB, false);
        sB = __builtin_amdgcn_fdot2(vhi(B7), ones, sB, false);
        float qB = __builtin_amdgcn_fdot2(vlo(B3), vlo(B3), 0.f, false);
        qB = __builtin_amdgcn_fdot2(vhi(B3), vhi(B3), qB, false);
        qB = __builtin_amdgcn_fdot2(vlo(B5), vlo(B5), qB, false);
        qB = __builtin_amdgcn_fdot2(vhi(B5), vhi(B5), qB, false);
        qB = __builtin_amdgcn_fdot2(vlo(B7), vlo(B7), qB, false);
        qB = __builtin_amdgcn_fdot2(vhi(B7), vhi(B7), qB, false);

        wave_sum2(sA, sB);
        wave_sum2(qA, qB);

        const float muA  = mA * sA * inv_n;
        const float varA = fmaxf((mA * mA) * qA * inv_n - muA * muA, 0.0f);
        const float rsA  = rsqrtf(varA + 1e-12f);
        const float aaA  = mA * rsA;
        const float ccA  = -muA * rsA;

        const float muB  = mB * sB * inv_n;
        const float varB = fmaxf((mB * mB) * qB * inv_n - muB * muB, 0.0f);
        const float rsB  = rsqrtf(varB + 1e-12f);
        const float aaB  = mB * rsB;
        const float ccB  = -muB * rsB;

        float* oA = out + (size_t)(p0 + 2 * i) * 768 + 4 * lane;
        float* oB = oA + 768;

        // six DISJOINT store-data registers; none redefined until next pair
        vfloat4 rA0, rA1, rA2, rB0, rB1, rB2;
        rA0.x = fmaf(fmaf((float)A3.x, aaA, ccA), ga[0][0], be[0][0]);
        rA0.y = fmaf(fmaf((float)A3.y, aaA, ccA), ga[0][1], be[0][1]);
        rA0.z = fmaf(fmaf((float)A3.z, aaA, ccA), ga[0][2], be[0][2]);
        rA0.w = fmaf(fmaf((float)A3.w, aaA, ccA), ga[0][3], be[0][3]);
        rA1.x = fmaf(fmaf((float)A5.x, aaA, ccA), ga[1][0], be[1][0]);
        rA1.y = fmaf(fmaf((float)A5.y, aaA, ccA), ga[1][1], be[1][1]);
        rA1.z = fmaf(fmaf((float)A5.z, aaA, ccA), ga[1][2], be[1][2]);
        rA1.w = fmaf(fmaf((float)A5.w, aaA, ccA), ga[1][3], be[1][3]);
        rA2.x = fmaf(fmaf((float)A7.x, aaA, ccA), ga[2][0], be[2][0]);
        rA2.y = fmaf(fmaf((float)A7.y, aaA, ccA), ga[2][1], be[2][1]);
        rA2.z = fmaf(fmaf((float)A7.z, aaA, ccA), ga[2][2], be[2][2]);
        rA2.w = fmaf(fmaf((float)A7.w, aaA, ccA), ga[2][3], be[2][3]);
        rB0.x = fmaf(fmaf((float)B3.x, aaB, ccB), ga[0][0], be[0][0]);
        rB0.y = fmaf(fmaf((float)B3.y, aaB, ccB), ga[0][1], be[0][1]);
        rB0.z = fmaf(fmaf((float)B3.z, aaB, ccB), ga[0][2], be[0][2]);
        rB0.w = fmaf(fmaf((float)B3.w, aaB, ccB), ga[0][3], be[0][3]);
        rB1.x = fmaf(fmaf((float)B5.x, aaB, ccB), ga[1][0], be[1][0]);
        rB1.y = fmaf(fmaf((float)B5.y, aaB, ccB), ga[1][1], be[1][1]);
        rB1.z = fmaf(fmaf((float)B5.z, aaB, ccB), ga[1][2], be[1][2]);
        rB1.w = fmaf(fmaf((float)B5.w, aaB, ccB), ga[1][3], be[1][3]);
        rB2.x = fmaf(fmaf((float)B7.x, aaB, ccB), ga[2][0], be[2][0]);
        rB2.y = fmaf(fmaf((float)B7.y, aaB, ccB), ga[2][1], be[2][1]);
        rB2.z = fmaf(fmaf((float)B7.z, aaB, ccB), ga[2][2], be[2][2]);
        rB2.w = fmaf(fmaf((float)B7.w, aaB, ccB), ga[2][3], be[2][3]);

        *reinterpret_cast<vfloat4*>(oA)       = rA0;
        *reinterpret_cast<vfloat4*>(oA + 256) = rA1;
        *reinterpret_cast<vfloat4*>(oA + 512) = rA2;
        *reinterpret_cast<vfloat4*>(oB)       = rB0;
        *reinterpret_cast<vfloat4*>(oB + 256) = rB1;
        *reinterpret_cast<vfloat4*>(oB + 512) = rB2;

        // rotate window addresses by 2; pull in the next two classes
        if (i < kPosPerWave / 2 - 1) {
            #pragma unroll
            for (int j = 0; j < 6; ++j) a[j] = a[j + 2];
            a[6] = (__builtin_amdgcn_readlane(myc, 2 * i + 8) << 9) + lane8;
            a[7] = (__builtin_amdgcn_readlane(myc, 2 * i + 9) << 9) + lane8;
        }
    }
}

} // namespace

extern "C" void kernel_launch(void* const* d_in, const int* in_sizes, int n_in,
                              void* d_out, int out_size, void* d_ws, size_t ws_size,
                              hipStream_t stream) {
    const int*   ids   = (const int*)  d_in[0];
    const float* mask  = (const float*)d_in[1];
    const float* W3    = (const float*)d_in[2];
    const float* W5    = (const float*)d_in[3];
    const float* W7    = (const float*)d_in[4];
    const float* gamma = (const float*)d_in[5];
    const float* beta  = (const float*)d_in[6];
    float*       out   = (float*)d_out;

    const int npos = in_sizes[0];              // B*L = 65536
    const int grid = npos / kBlkPos;           // 512 blocks; 2/CU -> one clean round

    hipLaunchKernelGGL(cnn_emb_ln, dim3(grid), dim3(kThreads), 0, stream,
                       ids, mask, W3, W5, W7, gamma, beta, out);
}